// Round 6
// baseline (88247.839 us; speedup 1.0000x reference)
//
#include <hip/hip_runtime.h>

#define T_ 1024
#define S_ 1024
#define H_ 2048
#define A_ 128
#define NBLK 256
#define THR 256

typedef __attribute__((ext_vector_type(8))) short short8;
typedef __attribute__((ext_vector_type(4))) float f32x4;

__device__ __forceinline__ float sigmf(float v) { return 1.0f / (1.0f + __expf(-v)); }

__device__ __forceinline__ ushort f2bf(float f) {
    uint u = __float_as_uint(f);
    return (ushort)((u + 0x7fffu + ((u >> 16) & 1u)) >> 16);
}
__device__ __forceinline__ float bflo(uint u) { return __uint_as_float(u << 16); }
__device__ __forceinline__ float bfhi(uint u) { return __uint_as_float(u & 0xffff0000u); }

__device__ __forceinline__ float wave_reduce(float a) {
#pragma unroll
    for (int off = 1; off < 64; off <<= 1) a += __shfl_xor(a, off);
    return a;
}

__device__ __forceinline__ void upk8(uint4 h, float* hv) {
    hv[0] = bflo(h.x); hv[1] = bfhi(h.x);
    hv[2] = bflo(h.y); hv[3] = bfhi(h.y);
    hv[4] = bflo(h.z); hv[5] = bfhi(h.z);
    hv[6] = bflo(h.w); hv[7] = bfhi(h.w);
}
__device__ __forceinline__ void macq(float& a, uint4 w, const float* hv) {
    a = fmaf(bflo(w.x), hv[0], a); a = fmaf(bfhi(w.x), hv[1], a);
    a = fmaf(bflo(w.y), hv[2], a); a = fmaf(bfhi(w.y), hv[3], a);
    a = fmaf(bflo(w.z), hv[4], a); a = fmaf(bfhi(w.z), hv[5], a);
    a = fmaf(bflo(w.w), hv[6], a); a = fmaf(bfhi(w.w), hv[7], a);
}
__device__ __forceinline__ uint4 pack8(const float* __restrict__ s) {
    const float4 f0 = *(const float4*)(s);
    const float4 f1 = *(const float4*)(s + 4);
    uint4 o;
    o.x = (uint)f2bf(f0.x) | ((uint)f2bf(f0.y) << 16);
    o.y = (uint)f2bf(f0.z) | ((uint)f2bf(f0.w) << 16);
    o.z = (uint)f2bf(f1.x) | ((uint)f2bf(f1.y) << 16);
    o.w = (uint)f2bf(f1.z) | ((uint)f2bf(f1.w) << 16);
    return o;
}

// ---------------- fp32 -> bf16 (RNE) packed conversion ----------------
__global__ void cvt_bf16(const float* __restrict__ src,
                         ushort* __restrict__ dst, int n4) {
    int i = blockIdx.x * blockDim.x + threadIdx.x;
    const int stride = gridDim.x * blockDim.x;
    for (; i < n4; i += stride) {
        const uint4 u = reinterpret_cast<const uint4*>(src)[i];
        ushort4 o;
        uint a;
        a = u.x; o.x = (ushort)((a + 0x7fffu + ((a >> 16) & 1u)) >> 16);
        a = u.y; o.y = (ushort)((a + 0x7fffu + ((a >> 16) & 1u)) >> 16);
        a = u.z; o.z = (ushort)((a + 0x7fffu + ((a >> 16) & 1u)) >> 16);
        a = u.w; o.w = (ushort)((a + 0x7fffu + ((a >> 16) & 1u)) >> 16);
        reinterpret_cast<ushort4*>(dst)[i] = o;
    }
}

// ---------------- X1 = x @ W_ih1^T + (b_ih1+b_hh1) : MFMA bf16 GEMM ----------------
__global__ __launch_bounds__(256, 2) void gemm_x1(
    const ushort* __restrict__ Abf, const ushort* __restrict__ Bbf,
    const float* __restrict__ bih1, const float* __restrict__ bhh1,
    float* __restrict__ X1) {
    __shared__ ushort At[64][80];
    __shared__ ushort Bt[64][80];
    const int tx = threadIdx.x;
    const int w = tx >> 6, lane = tx & 63;
    const int row0 = blockIdx.x * 64;
    const int col0 = blockIdx.y * 64;
    f32x4 acc[4];
#pragma unroll
    for (int n4 = 0; n4 < 4; ++n4) { acc[n4][0] = 0.f; acc[n4][1] = 0.f; acc[n4][2] = 0.f; acc[n4][3] = 0.f; }
    const int sr = tx >> 2, sc = (tx & 3) * 16;
    for (int k0 = 0; k0 < 1024; k0 += 64) {
        const uint4 a0 = *(const uint4*)(Abf + (size_t)(row0 + sr) * 1024 + k0 + sc);
        const uint4 a1 = *(const uint4*)(Abf + (size_t)(row0 + sr) * 1024 + k0 + sc + 8);
        const uint4 b0 = *(const uint4*)(Bbf + (size_t)(col0 + sr) * 1024 + k0 + sc);
        const uint4 b1 = *(const uint4*)(Bbf + (size_t)(col0 + sr) * 1024 + k0 + sc + 8);
        __syncthreads();
        *(uint4*)(&At[sr][sc]) = a0;
        *(uint4*)(&At[sr][sc + 8]) = a1;
        *(uint4*)(&Bt[sr][sc]) = b0;
        *(uint4*)(&Bt[sr][sc + 8]) = b1;
        __syncthreads();
#pragma unroll
        for (int kk = 0; kk < 64; kk += 32) {
            short8 af = *(const short8*)(&At[16 * w + (lane & 15)][kk + (lane >> 4) * 8]);
#pragma unroll
            for (int n4 = 0; n4 < 4; ++n4) {
                short8 bf = *(const short8*)(&Bt[n4 * 16 + (lane & 15)][kk + (lane >> 4) * 8]);
                acc[n4] = __builtin_amdgcn_mfma_f32_16x16x32_bf16(af, bf, acc[n4], 0, 0, 0);
            }
        }
    }
#pragma unroll
    for (int n4 = 0; n4 < 4; ++n4) {
        const int col = col0 + n4 * 16 + (lane & 15);
        const float bias = bih1[col] + bhh1[col];
#pragma unroll
        for (int r = 0; r < 4; ++r) {
            const int rowv = row0 + 16 * w + (lane >> 4) * 4 + r;
            X1[(size_t)rowv * 8192 + col] = acc[n4][r] + bias;
        }
    }
}

// ---------------- persistent LSTM: all recurrent weights in registers ----------------
// 256 threads (4 waves), 2 h-indices per wave, 1 wave/SIMD -> 512-reg budget.
// Pipelined: iteration t computes L1(t) and L2(t-1); single exchange per iter.
// PLAIN launch (no cooperative): residency guaranteed by grid=256 @ >=1 block/CU;
// only tag-spin + __syncthreads are used for ordering.
__global__ __launch_bounds__(THR, 1) void lstm_persist(
    const float* __restrict__ X1,
    const float* __restrict__ Whh1,
    const float* __restrict__ W2i, const float* __restrict__ W2h,
    const float* __restrict__ bih2, const float* __restrict__ bhh2,
    const float* __restrict__ Wlin, const float* __restrict__ blin,
    uint* __restrict__ th1, uint* __restrict__ th2,
    float* __restrict__ out)
{
    __shared__ ushort hc[4096];   // h1[t-1] (2048) || h2[t-2] (2048), bf16

    const int b = blockIdx.x, tid = threadIdx.x;
    const int w = tid >> 6, lane = tid & 63;
    const int j0 = b * 8 + w * 2;

    // ---- W_hh1 rows of this wave -> 32 uint4 (128 VGPR) ----
    uint4 w1[32];
#pragma unroll
    for (int r8 = 0; r8 < 8; ++r8) {
        const int R = (r8 & 3) * H_ + j0 + (r8 >> 2);
        const float* src = Whh1 + (size_t)R * H_;
#pragma unroll
        for (int p = 0; p < 4; ++p)
            w1[r8 * 4 + p] = pack8(src + p * 512 + lane * 8);
    }

    // ---- layer-2 concat rows -> 64 uint4 (256 VGPR) ----
    uint4 w2[64];
#pragma unroll
    for (int r8 = 0; r8 < 8; ++r8) {
        const int R = (r8 & 3) * H_ + j0 + (r8 >> 2);
        const float* si = W2i + (size_t)R * H_;
        const float* sh = W2h + (size_t)R * H_;
#pragma unroll
        for (int p = 0; p < 8; ++p) {
            const float* s = (p < 4) ? (si + p * 512 + lane * 8)
                                     : (sh + (p - 4) * 512 + lane * 8);
            w2[r8 * 8 + p] = pack8(s);
        }
    }

    // bias2 for lanes 0,1
    const int jj = j0 + (lane & 1);
    float b2g[4];
#pragma unroll
    for (int g = 0; g < 4; ++g) { const int R = g * H_ + jj; b2g[g] = bih2[R] + bhh2[R]; }

    float c1 = 0.f, c2 = 0.f;

#pragma unroll 1
    for (int t = 0; t <= T_; ++t) {
        // early X1 operand fetch (hidden under the exchange)
        float x1v = 0.f;
        if (t < T_ && lane < 8)
            x1v = X1[(size_t)t * 4 * H_ + (lane & 3) * H_ + j0 + (lane >> 2)];

        __syncthreads();   // all waves done reading hc from previous iter

        // ---- stage h1[t-1] and h2[t-2] into hc (tagged spin) ----
        {
            uint g0[8], g1[8];
            if (t >= 1) {
                const uint* s1 = th1 + ((t - 1) & 1) * H_ + tid * 8;
#pragma unroll
                for (int i = 0; i < 8; ++i)
                    g0[i] = __hip_atomic_load(&s1[i], __ATOMIC_RELAXED, __HIP_MEMORY_SCOPE_AGENT);
#pragma unroll
                for (int i = 0; i < 8; ++i)
                    while ((g0[i] >> 16) != (uint)(t - 1)) {
                        __builtin_amdgcn_s_sleep(1);
                        g0[i] = __hip_atomic_load(&s1[i], __ATOMIC_RELAXED, __HIP_MEMORY_SCOPE_AGENT);
                    }
            } else {
#pragma unroll
                for (int i = 0; i < 8; ++i) g0[i] = 0u;
            }
            if (t >= 2) {
                const uint* s2p = th2 + ((t - 1) & 1) * H_ + tid * 8;
#pragma unroll
                for (int i = 0; i < 8; ++i)
                    g1[i] = __hip_atomic_load(&s2p[i], __ATOMIC_RELAXED, __HIP_MEMORY_SCOPE_AGENT);
#pragma unroll
                for (int i = 0; i < 8; ++i)
                    while ((g1[i] >> 16) != (uint)(t - 1)) {
                        __builtin_amdgcn_s_sleep(1);
                        g1[i] = __hip_atomic_load(&s2p[i], __ATOMIC_RELAXED, __HIP_MEMORY_SCOPE_AGENT);
                    }
            } else {
#pragma unroll
                for (int i = 0; i < 8; ++i) g1[i] = 0u;
            }
            uint4 o0, o1;
            o0.x = (g0[0] & 0xffffu) | (g0[1] << 16); o0.y = (g0[2] & 0xffffu) | (g0[3] << 16);
            o0.z = (g0[4] & 0xffffu) | (g0[5] << 16); o0.w = (g0[6] & 0xffffu) | (g0[7] << 16);
            o1.x = (g1[0] & 0xffffu) | (g1[1] << 16); o1.y = (g1[2] & 0xffffu) | (g1[3] << 16);
            o1.z = (g1[4] & 0xffffu) | (g1[5] << 16); o1.w = (g1[6] & 0xffffu) | (g1[7] << 16);
            *(uint4*)(hc + tid * 8) = o0;
            *(uint4*)(hc + 2048 + tid * 8) = o1;
        }
        __syncthreads();

        // ---- L1(t): h1[t] = cell1(x[t], h1[t-1]) ----
        if (t < T_) {
            float s[8] = {0.f, 0.f, 0.f, 0.f, 0.f, 0.f, 0.f, 0.f};
#pragma unroll
            for (int p = 0; p < 4; ++p) {
                const uint4 hq = *(const uint4*)(hc + p * 512 + lane * 8);
                float hv[8]; upk8(hq, hv);
#pragma unroll
                for (int r8 = 0; r8 < 8; ++r8) macq(s[r8], w1[r8 * 4 + p], hv);
            }
#pragma unroll
            for (int r8 = 0; r8 < 8; ++r8) s[r8] = wave_reduce(s[r8]);
            float xg[4];
#pragma unroll
            for (int g = 0; g < 4; ++g) xg[g] = __shfl(x1v, (lane & 1) * 4 + g);
            if (lane < 2) {
                const float q0 = (lane & 1) ? s[4] : s[0];
                const float q1 = (lane & 1) ? s[5] : s[1];
                const float q2 = (lane & 1) ? s[6] : s[2];
                const float q3 = (lane & 1) ? s[7] : s[3];
                const float ig = sigmf(q0 + xg[0]);
                const float fg = sigmf(q1 + xg[1]);
                const float gv = tanhf(q2 + xg[2]);
                const float og = sigmf(q3 + xg[3]);
                c1 = fg * c1 + ig * gv;
                const float h1n = og * tanhf(c1);
                const uint pv = ((uint)t << 16) | (uint)f2bf(h1n);
                __hip_atomic_store(&th1[(t & 1) * H_ + j0 + (lane & 1)], pv,
                                   __ATOMIC_RELAXED, __HIP_MEMORY_SCOPE_AGENT);
            }
        }

        // ---- L2(t-1): h2[t-1] = cell2(h1[t-1], h2[t-2]) ----
        if (t >= 1) {
            float s2[8] = {0.f, 0.f, 0.f, 0.f, 0.f, 0.f, 0.f, 0.f};
#pragma unroll
            for (int p = 0; p < 8; ++p) {
                const uint4 hq = *(const uint4*)(hc + p * 512 + lane * 8);
                float hv[8]; upk8(hq, hv);
#pragma unroll
                for (int r8 = 0; r8 < 8; ++r8) macq(s2[r8], w2[r8 * 8 + p], hv);
            }
#pragma unroll
            for (int r8 = 0; r8 < 8; ++r8) s2[r8] = wave_reduce(s2[r8]);
            if (lane < 2) {
                const float q0 = (lane & 1) ? s2[4] : s2[0];
                const float q1 = (lane & 1) ? s2[5] : s2[1];
                const float q2 = (lane & 1) ? s2[6] : s2[2];
                const float q3 = (lane & 1) ? s2[7] : s2[3];
                const float ig = sigmf(q0 + b2g[0]);
                const float fg = sigmf(q1 + b2g[1]);
                const float gv = tanhf(q2 + b2g[2]);
                const float og = sigmf(q3 + b2g[3]);
                c2 = fg * c2 + ig * gv;
                const float h2n = og * tanhf(c2);
                const uint pv = ((uint)t << 16) | (uint)f2bf(h2n);
                __hip_atomic_store(&th2[(t & 1) * H_ + j0 + (lane & 1)], pv,
                                   __ATOMIC_RELAXED, __HIP_MEMORY_SCOPE_AGENT);
            }
        }
    }

    // ---- linear head on h2[T-1] (published at iter T_, slot 0, tag T_) ----
    if (b < 16) {
        __syncthreads();
        uint* src = th2 + (T_ & 1) * H_;
        for (int i2 = tid; i2 < H_ / 8; i2 += THR) {
            uint g0[8];
#pragma unroll
            for (int i = 0; i < 8; ++i) {
                g0[i] = __hip_atomic_load(&src[i2 * 8 + i], __ATOMIC_RELAXED, __HIP_MEMORY_SCOPE_AGENT);
                while ((g0[i] >> 16) != (uint)T_) {
                    __builtin_amdgcn_s_sleep(1);
                    g0[i] = __hip_atomic_load(&src[i2 * 8 + i], __ATOMIC_RELAXED, __HIP_MEMORY_SCOPE_AGENT);
                }
            }
            uint4 o0;
            o0.x = (g0[0] & 0xffffu) | (g0[1] << 16);
            o0.y = (g0[2] & 0xffffu) | (g0[3] << 16);
            o0.z = (g0[4] & 0xffffu) | (g0[5] << 16);
            o0.w = (g0[6] & 0xffffu) | (g0[7] << 16);
            *(uint4*)(hc + i2 * 8) = o0;
        }
        __syncthreads();
#pragma unroll
        for (int rr = 0; rr < 2; ++rr) {
            const int r = b * 8 + w * 2 + rr;
            const float* wrow = Wlin + (size_t)r * H_;
            float a = 0.f;
#pragma unroll
            for (int p = 0; p < 4; ++p) {
                const uint4 hq = *(const uint4*)(hc + p * 512 + lane * 8);
                float hv[8]; upk8(hq, hv);
                const float4 w0 = *(const float4*)(wrow + p * 512 + lane * 8);
                const float4 w1v = *(const float4*)(wrow + p * 512 + lane * 8 + 4);
                a = fmaf(w0.x, hv[0], a); a = fmaf(w0.y, hv[1], a);
                a = fmaf(w0.z, hv[2], a); a = fmaf(w0.w, hv[3], a);
                a = fmaf(w1v.x, hv[4], a); a = fmaf(w1v.y, hv[5], a);
                a = fmaf(w1v.z, hv[6], a); a = fmaf(w1v.w, hv[7], a);
            }
            a = wave_reduce(a);
            if (lane == 0) out[r] = a + blin[r];
        }
    }
}

extern "C" void kernel_launch(void* const* d_in, const int* in_sizes, int n_in,
                              void* d_out, int out_size, void* d_ws, size_t ws_size,
                              hipStream_t stream) {
    const float* x    = (const float*)d_in[0];
    const float* Wih1 = (const float*)d_in[1];
    const float* Whh1 = (const float*)d_in[2];
    const float* bih1 = (const float*)d_in[3];
    const float* bhh1 = (const float*)d_in[4];
    const float* Wih2 = (const float*)d_in[5];
    const float* Whh2 = (const float*)d_in[6];
    const float* bih2 = (const float*)d_in[7];
    const float* bhh2 = (const float*)d_in[8];
    const float* Wlin = (const float*)d_in[9];
    const float* blin = (const float*)d_in[10];
    float* out = (float*)d_out;

    // ws layout (bytes):
    // [0, 33554432)          X1   [1024][8192] f32
    // [33554432, 35651584)   x_bf16 [1024][1024]
    // [35651584, 52428800)   W1i_bf16 [8192][1024]
    // [52428800, 52445184)   th1  [2][2048] u32 (tagged h1)
    // [52445184, 52461568)   th2  [2][2048] u32 (tagged h2)
    float*  X1    = (float*)d_ws;
    ushort* xbf   = (ushort*)((char*)d_ws + 33554432);
    ushort* w1ibf = (ushort*)((char*)d_ws + 35651584);
    uint*   th1   = (uint*)((char*)d_ws + 52428800);
    uint*   th2   = (uint*)((char*)d_ws + 52445184);

    hipLaunchKernelGGL(cvt_bf16, dim3(512), dim3(256), 0, stream, x, xbf, 262144);
    hipLaunchKernelGGL(cvt_bf16, dim3(2048), dim3(256), 0, stream, Wih1, w1ibf, 2097152);
    hipLaunchKernelGGL(gemm_x1, dim3(16, 128), dim3(256), 0, stream,
                       (const ushort*)xbf, (const ushort*)w1ibf, bih1, bhh1, X1);
    hipMemsetAsync((void*)th1, 0xFF, 32768, stream);   // covers th1+th2 (32 KB)

    hipLaunchKernelGGL(lstm_persist, dim3(NBLK), dim3(THR), 0, stream,
                       X1, Whh1, Wih2, Whh2, bih2, bhh2, Wlin, blin,
                       th1, th2, out);
}

// Round 7
// 7284.991 us; speedup vs baseline: 12.1137x; 12.1137x over previous
//
#include <hip/hip_runtime.h>

#define T_ 1024
#define S_ 1024
#define H_ 2048
#define A_ 128
#define NBLK 256
#define THR 256

typedef __attribute__((ext_vector_type(8))) short short8;
typedef __attribute__((ext_vector_type(4))) float f32x4;

__device__ __forceinline__ float sigmf(float v) { return 1.0f / (1.0f + __expf(-v)); }

__device__ __forceinline__ ushort f2bf(float f) {
    uint u = __float_as_uint(f);
    return (ushort)((u + 0x7fffu + ((u >> 16) & 1u)) >> 16);
}

__device__ __forceinline__ short8 pack8(const float* __restrict__ s) {
    const float4 f0 = *(const float4*)(s);
    const float4 f1 = *(const float4*)(s + 4);
    uint4 o;
    o.x = (uint)f2bf(f0.x) | ((uint)f2bf(f0.y) << 16);
    o.y = (uint)f2bf(f0.z) | ((uint)f2bf(f0.w) << 16);
    o.z = (uint)f2bf(f1.x) | ((uint)f2bf(f1.y) << 16);
    o.w = (uint)f2bf(f1.z) | ((uint)f2bf(f1.w) << 16);
    return __builtin_bit_cast(short8, o);
}

// ---------------- fp32 -> bf16 (RNE) packed conversion ----------------
__global__ void cvt_bf16(const float* __restrict__ src,
                         ushort* __restrict__ dst, int n4) {
    int i = blockIdx.x * blockDim.x + threadIdx.x;
    const int stride = gridDim.x * blockDim.x;
    for (; i < n4; i += stride) {
        const uint4 u = reinterpret_cast<const uint4*>(src)[i];
        ushort4 o;
        uint a;
        a = u.x; o.x = (ushort)((a + 0x7fffu + ((a >> 16) & 1u)) >> 16);
        a = u.y; o.y = (ushort)((a + 0x7fffu + ((a >> 16) & 1u)) >> 16);
        a = u.z; o.z = (ushort)((a + 0x7fffu + ((a >> 16) & 1u)) >> 16);
        a = u.w; o.w = (ushort)((a + 0x7fffu + ((a >> 16) & 1u)) >> 16);
        reinterpret_cast<ushort4*>(dst)[i] = o;
    }
}

// ---------------- X1 = x @ W_ih1^T + (b_ih1+b_hh1) : MFMA bf16 GEMM ----------------
__global__ __launch_bounds__(256, 2) void gemm_x1(
    const ushort* __restrict__ Abf, const ushort* __restrict__ Bbf,
    const float* __restrict__ bih1, const float* __restrict__ bhh1,
    float* __restrict__ X1) {
    __shared__ ushort At[64][80];
    __shared__ ushort Bt[64][80];
    const int tx = threadIdx.x;
    const int w = tx >> 6, lane = tx & 63;
    const int row0 = blockIdx.x * 64;
    const int col0 = blockIdx.y * 64;
    f32x4 acc[4];
#pragma unroll
    for (int n4 = 0; n4 < 4; ++n4) { acc[n4][0] = 0.f; acc[n4][1] = 0.f; acc[n4][2] = 0.f; acc[n4][3] = 0.f; }
    const int sr = tx >> 2, sc = (tx & 3) * 16;
    for (int k0 = 0; k0 < 1024; k0 += 64) {
        const uint4 a0 = *(const uint4*)(Abf + (size_t)(row0 + sr) * 1024 + k0 + sc);
        const uint4 a1 = *(const uint4*)(Abf + (size_t)(row0 + sr) * 1024 + k0 + sc + 8);
        const uint4 b0 = *(const uint4*)(Bbf + (size_t)(col0 + sr) * 1024 + k0 + sc);
        const uint4 b1 = *(const uint4*)(Bbf + (size_t)(col0 + sr) * 1024 + k0 + sc + 8);
        __syncthreads();
        *(uint4*)(&At[sr][sc]) = a0;
        *(uint4*)(&At[sr][sc + 8]) = a1;
        *(uint4*)(&Bt[sr][sc]) = b0;
        *(uint4*)(&Bt[sr][sc + 8]) = b1;
        __syncthreads();
#pragma unroll
        for (int kk = 0; kk < 64; kk += 32) {
            short8 af = *(const short8*)(&At[16 * w + (lane & 15)][kk + (lane >> 4) * 8]);
#pragma unroll
            for (int n4 = 0; n4 < 4; ++n4) {
                short8 bf = *(const short8*)(&Bt[n4 * 16 + (lane & 15)][kk + (lane >> 4) * 8]);
                acc[n4] = __builtin_amdgcn_mfma_f32_16x16x32_bf16(af, bf, acc[n4], 0, 0, 0);
            }
        }
    }
#pragma unroll
    for (int n4 = 0; n4 < 4; ++n4) {
        const int col = col0 + n4 * 16 + (lane & 15);
        const float bias = bih1[col] + bhh1[col];
#pragma unroll
        for (int r = 0; r < 4; ++r) {
            const int rowv = row0 + 16 * w + (lane >> 4) * 4 + r;
            X1[(size_t)rowv * 8192 + col] = acc[n4][r] + bias;
        }
    }
}

// ---------------- persistent LSTM: weights as MFMA A-fragments (AGPR-resident) --------
// 256 threads (4 waves), 1 wave/SIMD -> 512-reg unified budget per lane.
// Row map r in [0,32): r = j_local*4 + gate. L1: K=2048 split 512/wave over h1.
// L2: K=4096 split 1024/wave over [h1;h2] (waves 0,1 -> W2i; waves 2,3 -> W2h).
// Pipelined: iter t computes L1(t) and L2(t-1); one tagged global exchange/iter.
__global__ __launch_bounds__(THR, 1) void lstm_mfma(
    const float* __restrict__ X1,
    const float* __restrict__ Whh1,
    const float* __restrict__ W2i, const float* __restrict__ W2h,
    const float* __restrict__ bih2, const float* __restrict__ bhh2,
    const float* __restrict__ Wlin, const float* __restrict__ blin,
    uint* __restrict__ th1, uint* __restrict__ th2,
    float* __restrict__ out)
{
    __shared__ ushort hc[4096];    // h1[t-1] (2048) || h2[t-2] (2048) bf16
    __shared__ float pl[4][64];    // per-wave K-partials, 64 rows (32 L1 + 32 L2)
    __shared__ float sums[64];

    const int b = blockIdx.x, tid = threadIdx.x;
    const int w = tid >> 6, lane = tid & 63;
    const int j0 = b * 8;
    const int m = lane & 15;          // MFMA row within 16-group
    const int ko = (lane >> 4) * 8;   // k-octet within a 32-chunk

    // ---- prologue: weight fragments (MFMA A layout), fp32 -> bf16 ----
    short8 a1[2][16];                 // 128 regs
#pragma unroll
    for (int g = 0; g < 2; ++g) {
        const int r = g * 16 + m;
        const int R = (r & 3) * H_ + j0 + (r >> 2);
        const float* src = Whh1 + (size_t)R * H_ + w * 512 + ko;
#pragma unroll
        for (int c = 0; c < 16; ++c)
            a1[g][c] = pack8(src + c * 32);
    }
    short8 a2[2][32];                 // 256 regs
#pragma unroll
    for (int g = 0; g < 2; ++g) {
        const int r = g * 16 + m;
        const int R = (r & 3) * H_ + j0 + (r >> 2);
        const float* base = (w < 2) ? (W2i + (size_t)R * H_ + w * 1024 + ko)
                                    : (W2h + (size_t)R * H_ + (w - 2) * 1024 + ko);
#pragma unroll
        for (int c = 0; c < 32; ++c)
            a2[g][c] = pack8(base + c * 32);
    }

    // per-thread cell state & L2 bias (threads 0..7: c1/j, threads 8..15: c2/j)
    float c1 = 0.f, c2 = 0.f;
    float b2g[4] = {0.f, 0.f, 0.f, 0.f};
    if (tid >= 8 && tid < 16) {
        const int jl = tid - 8;
#pragma unroll
        for (int g = 0; g < 4; ++g) {
            const int R = g * H_ + j0 + jl;
            b2g[g] = bih2[R] + bhh2[R];
        }
    }

#pragma unroll 1
    for (int t = 0; t <= T_; ++t) {
        // early per-thread X1 fetch (threads 0..7), hidden under the exchange
        float xg[4] = {0.f, 0.f, 0.f, 0.f};
        if (tid < 8 && t < T_) {
#pragma unroll
            for (int g = 0; g < 4; ++g)
                xg[g] = X1[(size_t)t * 8192 + g * H_ + j0 + tid];
        }

        // ---- stage h1[t-1] and h2[t-2] into hc (tagged spin) ----
        {
            uint g0[8], g1[8];
            if (t >= 1) {
                const uint* s1 = th1 + ((t - 1) & 1) * H_ + tid * 8;
#pragma unroll
                for (int i = 0; i < 8; ++i)
                    g0[i] = __hip_atomic_load(&s1[i], __ATOMIC_RELAXED, __HIP_MEMORY_SCOPE_AGENT);
#pragma unroll
                for (int i = 0; i < 8; ++i)
                    while ((g0[i] >> 16) != (uint)(t - 1)) {
                        __builtin_amdgcn_s_sleep(1);
                        g0[i] = __hip_atomic_load(&s1[i], __ATOMIC_RELAXED, __HIP_MEMORY_SCOPE_AGENT);
                    }
            } else {
#pragma unroll
                for (int i = 0; i < 8; ++i) g0[i] = 0u;
            }
            if (t >= 2) {
                const uint* s2p = th2 + ((t - 1) & 1) * H_ + tid * 8;
#pragma unroll
                for (int i = 0; i < 8; ++i)
                    g1[i] = __hip_atomic_load(&s2p[i], __ATOMIC_RELAXED, __HIP_MEMORY_SCOPE_AGENT);
#pragma unroll
                for (int i = 0; i < 8; ++i)
                    while ((g1[i] >> 16) != (uint)(t - 1)) {
                        __builtin_amdgcn_s_sleep(1);
                        g1[i] = __hip_atomic_load(&s2p[i], __ATOMIC_RELAXED, __HIP_MEMORY_SCOPE_AGENT);
                    }
            } else {
#pragma unroll
                for (int i = 0; i < 8; ++i) g1[i] = 0u;
            }
            uint4 o0, o1;
            o0.x = (g0[0] & 0xffffu) | (g0[1] << 16); o0.y = (g0[2] & 0xffffu) | (g0[3] << 16);
            o0.z = (g0[4] & 0xffffu) | (g0[5] << 16); o0.w = (g0[6] & 0xffffu) | (g0[7] << 16);
            o1.x = (g1[0] & 0xffffu) | (g1[1] << 16); o1.y = (g1[2] & 0xffffu) | (g1[3] << 16);
            o1.z = (g1[4] & 0xffffu) | (g1[5] << 16); o1.w = (g1[6] & 0xffffu) | (g1[7] << 16);
            *(uint4*)(hc + tid * 8) = o0;
            *(uint4*)(hc + 2048 + tid * 8) = o1;
        }
        __syncthreads();   // bar1: hc ready

        // ---- MFMA matvec: L1 over h1-slice, L2 over hcat-slice ----
        f32x4 acc0, acc1, acc2, acc3;
#pragma unroll
        for (int r = 0; r < 4; ++r) { acc0[r] = 0.f; acc1[r] = 0.f; acc2[r] = 0.f; acc3[r] = 0.f; }
        const ushort* h1s = hc + w * 512;
        const ushort* hcs = hc + w * 1024;
#pragma unroll
        for (int c = 0; c < 16; ++c) {
            const short8 bfr = *(const short8*)(h1s + c * 32 + ko);   // LDS broadcast
            acc0 = __builtin_amdgcn_mfma_f32_16x16x32_bf16(a1[0][c], bfr, acc0, 0, 0, 0);
            acc1 = __builtin_amdgcn_mfma_f32_16x16x32_bf16(a1[1][c], bfr, acc1, 0, 0, 0);
        }
#pragma unroll
        for (int c = 0; c < 32; ++c) {
            const short8 bfr = *(const short8*)(hcs + c * 32 + ko);
            acc2 = __builtin_amdgcn_mfma_f32_16x16x32_bf16(a2[0][c], bfr, acc2, 0, 0, 0);
            acc3 = __builtin_amdgcn_mfma_f32_16x16x32_bf16(a2[1][c], bfr, acc3, 0, 0, 0);
        }
        // col-0 lanes write K-partials: lane 16q holds rows 4q..4q+3 of each group
        if (m == 0) {
            const int r4 = (lane >> 4) * 4;
#pragma unroll
            for (int r = 0; r < 4; ++r) {
                pl[w][ 0 + r4 + r] = acc0[r];
                pl[w][16 + r4 + r] = acc1[r];
                pl[w][32 + r4 + r] = acc2[r];
                pl[w][48 + r4 + r] = acc3[r];
            }
        }
        __syncthreads();   // bar2: partials ready
        if (tid < 64) sums[tid] = pl[0][tid] + pl[1][tid] + pl[2][tid] + pl[3][tid];
        __syncthreads();   // bar3: sums ready

        // ---- gate math + publish ----
        if (tid < 8 && t < T_) {           // L1 cell for j = j0+tid
            const float ig = sigmf(sums[tid * 4 + 0] + xg[0]);
            const float fg = sigmf(sums[tid * 4 + 1] + xg[1]);
            const float gv = tanhf(sums[tid * 4 + 2] + xg[2]);
            const float og = sigmf(sums[tid * 4 + 3] + xg[3]);
            c1 = fg * c1 + ig * gv;
            const float h1n = og * tanhf(c1);
            const uint pv = ((uint)t << 16) | (uint)f2bf(h1n);
            __hip_atomic_store(&th1[(t & 1) * H_ + j0 + tid], pv,
                               __ATOMIC_RELAXED, __HIP_MEMORY_SCOPE_AGENT);
        }
        if (tid >= 8 && tid < 16 && t >= 1) {   // L2 cell (step t-1) for j = j0+tid-8
            const int jl = tid - 8;
            const float ig = sigmf(sums[32 + jl * 4 + 0] + b2g[0]);
            const float fg = sigmf(sums[32 + jl * 4 + 1] + b2g[1]);
            const float gv = tanhf(sums[32 + jl * 4 + 2] + b2g[2]);
            const float og = sigmf(sums[32 + jl * 4 + 3] + b2g[3]);
            c2 = fg * c2 + ig * gv;
            const float h2n = og * tanhf(c2);
            const uint pv = ((uint)t << 16) | (uint)f2bf(h2n);
            __hip_atomic_store(&th2[(t & 1) * H_ + j0 + jl], pv,
                               __ATOMIC_RELAXED, __HIP_MEMORY_SCOPE_AGENT);
        }
    }

    // ---- linear head on h2[T-1] (tag T_, slot 0) : blocks 0..15, 8 rows each ----
    if (b < 16) {
        __syncthreads();
        {
            const uint* sp = th2 + (T_ & 1) * H_ + tid * 8;
            uint gg[8];
#pragma unroll
            for (int i = 0; i < 8; ++i) {
                gg[i] = __hip_atomic_load(&sp[i], __ATOMIC_RELAXED, __HIP_MEMORY_SCOPE_AGENT);
                while ((gg[i] >> 16) != (uint)T_) {
                    __builtin_amdgcn_s_sleep(1);
                    gg[i] = __hip_atomic_load(&sp[i], __ATOMIC_RELAXED, __HIP_MEMORY_SCOPE_AGENT);
                }
            }
            uint4 o;
            o.x = (gg[0] & 0xffffu) | (gg[1] << 16);
            o.y = (gg[2] & 0xffffu) | (gg[3] << 16);
            o.z = (gg[4] & 0xffffu) | (gg[5] << 16);
            o.w = (gg[6] & 0xffffu) | (gg[7] << 16);
            *(uint4*)(hc + tid * 8) = o;
        }
        __syncthreads();
#pragma unroll
        for (int rr = 0; rr < 2; ++rr) {
            const int r = b * 8 + w * 2 + rr;
            const float* wrow = Wlin + (size_t)r * H_;
            float a = 0.f;
#pragma unroll
            for (int p = 0; p < 4; ++p) {
                const int o8 = p * 512 + lane * 8;
                const uint4 hq = *(const uint4*)(hc + o8);
                float hv[8];
                hv[0] = __uint_as_float(hq.x << 16); hv[1] = __uint_as_float(hq.x & 0xffff0000u);
                hv[2] = __uint_as_float(hq.y << 16); hv[3] = __uint_as_float(hq.y & 0xffff0000u);
                hv[4] = __uint_as_float(hq.z << 16); hv[5] = __uint_as_float(hq.z & 0xffff0000u);
                hv[6] = __uint_as_float(hq.w << 16); hv[7] = __uint_as_float(hq.w & 0xffff0000u);
                const float4 w0 = *(const float4*)(wrow + o8);
                const float4 w1v = *(const float4*)(wrow + o8 + 4);
                a = fmaf(w0.x, hv[0], a); a = fmaf(w0.y, hv[1], a);
                a = fmaf(w0.z, hv[2], a); a = fmaf(w0.w, hv[3], a);
                a = fmaf(w1v.x, hv[4], a); a = fmaf(w1v.y, hv[5], a);
                a = fmaf(w1v.z, hv[6], a); a = fmaf(w1v.w, hv[7], a);
            }
#pragma unroll
            for (int off = 1; off < 64; off <<= 1) a += __shfl_xor(a, off);
            if (lane == 0) out[r] = a + blin[r];
        }
    }
}

extern "C" void kernel_launch(void* const* d_in, const int* in_sizes, int n_in,
                              void* d_out, int out_size, void* d_ws, size_t ws_size,
                              hipStream_t stream) {
    const float* x    = (const float*)d_in[0];
    const float* Wih1 = (const float*)d_in[1];
    const float* Whh1 = (const float*)d_in[2];
    const float* bih1 = (const float*)d_in[3];
    const float* bhh1 = (const float*)d_in[4];
    const float* Wih2 = (const float*)d_in[5];
    const float* Whh2 = (const float*)d_in[6];
    const float* bih2 = (const float*)d_in[7];
    const float* bhh2 = (const float*)d_in[8];
    const float* Wlin = (const float*)d_in[9];
    const float* blin = (const float*)d_in[10];
    float* out = (float*)d_out;

    // ws layout (bytes):
    // [0, 33554432)          X1   [1024][8192] f32
    // [33554432, 35651584)   x_bf16 [1024][1024]
    // [35651584, 52428800)   W1i_bf16 [8192][1024]
    // [52428800, 52445184)   th1  [2][2048] u32 (tagged h1)
    // [52445184, 52461568)   th2  [2][2048] u32 (tagged h2)
    float*  X1    = (float*)d_ws;
    ushort* xbf   = (ushort*)((char*)d_ws + 33554432);
    ushort* w1ibf = (ushort*)((char*)d_ws + 35651584);
    uint*   th1   = (uint*)((char*)d_ws + 52428800);
    uint*   th2   = (uint*)((char*)d_ws + 52445184);

    hipLaunchKernelGGL(cvt_bf16, dim3(512), dim3(256), 0, stream, x, xbf, 262144);
    hipLaunchKernelGGL(cvt_bf16, dim3(2048), dim3(256), 0, stream, Wih1, w1ibf, 2097152);
    hipLaunchKernelGGL(gemm_x1, dim3(16, 128), dim3(256), 0, stream,
                       (const ushort*)xbf, (const ushort*)w1ibf, bih1, bhh1, X1);
    hipMemsetAsync((void*)th1, 0xFF, 32768, stream);   // covers th1+th2 (32 KB)

    hipLaunchKernelGGL(lstm_mfma, dim3(NBLK), dim3(THR), 0, stream,
                       X1, Whh1, Wih2, Whh2, bih2, bhh2, Wlin, blin,
                       th1, th2, out);
}